// Round 11
// baseline (29.446 us; speedup 1.0000x reference)
//
#include <hip/hip_runtime.h>

// Problem: B=32,S=256,C=50,L=20,F=30,W=3. out[p,c*30+f] = max_k(conv)+bias
constexpr int Cc = 50, Lc = 20, Fc = 30, Wc = 3;
constexpr int OUT_CH   = 1500;
constexpr int CONV_LEN = 18;
constexpr int XSZ      = 1000;          // floats per position slab (4000 B)
constexpr int NPOS     = 8192;
constexpr int BLOCK    = 256;           // 4 waves/block
constexpr int CHB      = 384;           // channels per wave-task (64 lanes x 6)
constexpr int NB       = 4;             // channel-blocks per position (384*3+348)
constexpr int T        = 8;             // positions per wave (weights amortized 8x)
constexpr int STRIPF   = 280;           // floats per strip (14 rows = 1120 B)
// waves = NB * NPOS/T = 4096 -> 1024 blocks. ZERO barriers: each wave stages its
// own 13-14 rows into a wave-private LDS strip via global_load_lds and syncs only
// with its own counted vmcnt (T4): prefetch for task t+1 never drains.

typedef __attribute__((address_space(1))) const void* gas_t;
typedef __attribute__((address_space(3))) void*       las_t;

static __device__ __forceinline__ void gll16(const float* g, float* l) {
    // dst = uniform LDS base; HW writes base + lane*16 from per-lane g.
    __builtin_amdgcn_global_load_lds((gas_t)g, (las_t)l, 16, 0, 0);
}

__global__ __launch_bounds__(BLOCK, 6)
void charcnn_kernel(const float* __restrict__ x,      // [8192, 50, 20]
                    const float* __restrict__ weight, // [1500, 1, 3]
                    const float* __restrict__ bias,   // [1500]
                    float* __restrict__ out)          // [8192, 1500]
{
    __shared__ float strips[4][2][STRIPF];            // per-wave double-buffered strip

    const int lane = threadIdx.x & 63;
    const int w4   = threadIdx.x >> 6;                // wave within block
    const int W    = blockIdx.x * 4 + w4;             // global wave id, 0..4095
    const int b    = W >> 10;                         // channel-block 0..3
    const int p0   = (W & 1023) * T;                  // first position

    // ---- wave-uniform staging geometry (b=3 block has 348 ch, 12 rows)
    const int ch0  = b * CHB;
    const int nl   = (b == 3) ? 58 : 64;              // active lanes
    const int r0   = ch0 / 30;                        // first row staged
    const int L1   = (b == 3) ? 60 : 64;              // inst1 lanes (16 B each)
    const int OFF2 = (b == 3) ? 216 : 256;            // inst2 float offset (tail)

    // ---- per-lane channel geometry
    const int chL   = min(ch0 + 6 * lane, OUT_CH - 6);   // clamp idle lanes (b=3)
    const int cLoc  = (ch0 + 6 * lane) / 30 - r0;        // row index inside strip

    // ---- weights/bias ONCE per wave lifetime (register-resident, 8 positions)
    float w[18], bb[6];
    {
        const float2* wp = (const float2*)(weight + chL * 3);
        #pragma unroll
        for (int i = 0; i < 9; ++i) { float2 q = wp[i]; w[2*i] = q.x; w[2*i+1] = q.y; }
        const float2* bp = (const float2*)(bias + chL);
        #pragma unroll
        for (int i = 0; i < 3; ++i) { float2 q = bp[i]; bb[2*i] = q.x; bb[2*i+1] = q.y; }
    }

    float* strip0 = &strips[w4][0][0];
    float* strip1 = &strips[w4][1][0];
    const float* gband = x + (size_t)p0 * XSZ + r0 * Lc;  // rows r0.. of slab p0

    // ---- prologue: stage strip for task 0   [outstanding: 2]
    if (lane < L1) gll16(gband + lane * 4, strip0);
    if (lane < 6)  gll16(gband + OFF2 + lane * 4, strip0 + OFF2);

    #pragma unroll
    for (int t = 0; t < T; ++t) {
        float* cur = (t & 1) ? strip1 : strip0;
        float* nxt = (t & 1) ? strip0 : strip1;

        // issue next task's stage first (stays in flight through this compute)
        if (t + 1 < T) {
            const float* gb = gband + (size_t)(t + 1) * XSZ;
            if (lane < L1) gll16(gb + lane * 4, nxt);
            if (lane < 6)  gll16(gb + OFF2 + lane * 4, nxt + OFF2);
        }

        // counted vmcnt (T4): retire ONLY this task's 2 glls. In flight behind
        // them: next stage (2) + previous task's 3 stores -> 5; tail: 3.
        if (t == 0)          asm volatile("s_waitcnt vmcnt(2)" ::: "memory");
        else if (t + 1 < T)  asm volatile("s_waitcnt vmcnt(5)" ::: "memory");
        else                 asm volatile("s_waitcnt vmcnt(3)" ::: "memory");
        __builtin_amdgcn_sched_barrier(0);

        // own row: 80 B at strip + cLoc*80, 16B-aligned -> 5x ds_read_b128
        float v[Lc];
        {
            const float4* rowv = (const float4*)(cur + cLoc * Lc);
            #pragma unroll
            for (int i = 0; i < Lc / 4; ++i) {
                const float4 q = rowv[i];
                v[4*i+0] = q.x; v[4*i+1] = q.y; v[4*i+2] = q.z; v[4*i+3] = q.w;
            }
        }

        float res[6];
        #pragma unroll
        for (int j = 0; j < 6; ++j) {
            const float w0 = w[3*j + 0];
            const float w1 = w[3*j + 1];
            const float w2 = w[3*j + 2];

            float m = fmaf(v[0], w0, fmaf(v[1], w1, v[2] * w2));
            #pragma unroll
            for (int q = 1; q + 1 < CONV_LEN; q += 2) {
                const float a = fmaf(v[q],   w0, fmaf(v[q+1], w1, v[q+2] * w2));
                const float c = fmaf(v[q+1], w0, fmaf(v[q+2], w1, v[q+3] * w2));
                m = fmaxf(fmaxf(m, a), c);                  // v_max3
            }
            m = fmaxf(m, fmaf(v[CONV_LEN-1], w0,
                       fmaf(v[CONV_LEN],     w1, v[CONV_LEN+1] * w2)));
            res[j] = m + bb[j];         // bias invariant over window
        }

        if (lane < nl) {                // 3 stores (counted in the vmcnt budget)
            float2* op = (float2*)(out + (size_t)(p0 + t) * OUT_CH + ch0 + 6 * lane);
            #pragma unroll
            for (int i = 0; i < 3; ++i) op[i] = make_float2(res[2*i], res[2*i+1]);
        }
    }
}

extern "C" void kernel_launch(void* const* d_in, const int* in_sizes, int n_in,
                              void* d_out, int out_size, void* d_ws, size_t ws_size,
                              hipStream_t stream) {
    const float* x      = (const float*)d_in[0];
    const float* weight = (const float*)d_in[1];
    const float* bias   = (const float*)d_in[2];
    float* out          = (float*)d_out;

    charcnn_kernel<<<1024, BLOCK, 0, stream>>>(x, weight, bias, out);  // 4096 waves
}

// Round 12
// 28.870 us; speedup vs baseline: 1.0200x; 1.0200x over previous
//
#include <hip/hip_runtime.h>

// Problem constants (from reference): B=32, S=256, C=50, L=20, F=30, W=3
constexpr int Bc = 32;
constexpr int Sc = 256;
constexpr int Cc = 50;
constexpr int Lc = 20;
constexpr int Fc = 30;
constexpr int Wc = 3;
constexpr int OUT_CH   = Cc * Fc;       // 1500
constexpr int CONV_LEN = Lc - Wc + 1;   // 18 -> 9 packed window-pairs
constexpr int NPAIR    = CONV_LEN / 2;  // 9
constexpr int XSZ      = Cc * Lc;       // 1000 floats per (b,s)
constexpr int BLOCK    = 512;           // 8 waves/block (R8 shell - best so far)
constexpr int CH_PER_T = 3;             // 3t..3t+2 never crosses a group boundary
constexpr int NP       = 8;             // positions per block -> 1024 blocks
constexpr int ACT      = OUT_CH / CH_PER_T;   // 500 active compute lanes
constexpr int STG      = XSZ / 4;             // 250 stager lanes

typedef float f32x2 __attribute__((ext_vector_type(2)));
typedef float f32x4 __attribute__((ext_vector_type(4)));

// Packed fp32 VOP3P (CDNA2+): 2 fp32 ops per instruction, fma rounding.
static __device__ __forceinline__ f32x2 pk_fma(f32x2 a, f32x2 b, f32x2 c) {
    f32x2 d;
    asm("v_pk_fma_f32 %0, %1, %2, %3" : "=v"(d) : "v"(a), "v"(b), "v"(c));
    return d;
}
static __device__ __forceinline__ f32x2 pk_mul(f32x2 a, f32x2 b) {
    f32x2 d;
    asm("v_pk_mul_f32 %0, %1, %2" : "=v"(d) : "v"(a), "v"(b));
    return d;
}

// Barrier with lgkmcnt(0) only (proven R4-R9): own ds ops retired; global
// prefetch loads stay in flight across the barrier.
static __device__ __forceinline__ void block_sync() {
    asm volatile("s_waitcnt lgkmcnt(0)" ::: "memory");
    __builtin_amdgcn_s_barrier();
    asm volatile("" ::: "memory");
}

// (512, 6): 6 waves/EU -> <=85 VGPR, 24 waves/CU; reg budget ~75 fits.
__global__ __launch_bounds__(BLOCK, 6)
void charcnn_kernel(const float* __restrict__ x,      // [B*S, C, L]
                    const float* __restrict__ weight, // [C*F, 1, W]
                    const float* __restrict__ bias,   // [C*F]
                    float* __restrict__ out)          // [B*S, C*F]
{
    __shared__ float xs[2][XSZ];        // double-buffered 4 KB slabs

    const int t    = threadIdx.x;
    const int pos0 = blockIdx.x * NP;
    const bool on  = (t < ACT);         // 500 compute lanes
    const bool stg = (t < STG);         // 250 staging lanes

    // ---- weights as broadcast pairs (9 pairs = 18 VGPR) + bias, ONCE.
    f32x2 wp2[CH_PER_T * Wc];
    float bb[CH_PER_T];
    if (on) {
        const float* wp = weight + t * (CH_PER_T * Wc);
        #pragma unroll
        for (int i = 0; i < CH_PER_T * Wc; ++i) {
            const float q = wp[i];
            wp2[i][0] = q; wp2[i][1] = q;
        }
        const float* bp = bias + t * CH_PER_T;
        #pragma unroll
        for (int i = 0; i < CH_PER_T; ++i) bb[i] = bp[i];
    }

    const int c = t / 10;               // group shared by this thread's 3 channels

    // ---- prologue: stage slab0 into xs[0]
    if (stg)
        ((float4*)xs[0])[t] = ((const float4*)(x + (size_t)pos0 * XSZ))[t];
    block_sync();

    #pragma unroll 2
    for (int p = 0; p < NP; ++p) {
        const int buf = p & 1;

        // Next slab's load first: latency hides under this position's compute.
        float4 preA;
        if (stg && (p + 1 < NP))
            preA = ((const float4*)(x + (size_t)(pos0 + p + 1) * XSZ))[t];

        if (on) {
            // Row: 80 B -> 5x ds_read_b128 -> 10 even pairs, register-free splits.
            f32x2 ev[Lc / 2];
            {
                const f32x4* rowv = (const f32x4*)(xs[buf] + c * Lc);
                #pragma unroll
                for (int i = 0; i < Lc / 4; ++i) {
                    const f32x4 q = rowv[i];
                    ev[2*i]   = __builtin_shufflevector(q, q, 0, 1);
                    ev[2*i+1] = __builtin_shufflevector(q, q, 2, 3);
                }
            }
            // Odd pairs (v[2i+1], v[2i+2]): register movs only, built once per
            // row, shared by the 3 filters (amortized 6 insts/filter).
            f32x2 od[NPAIR];
            #pragma unroll
            for (int i = 0; i < NPAIR; ++i) {
                od[i][0] = ev[i][1];
                od[i][1] = ev[i + 1][0];
            }

            float* op = out + (size_t)(pos0 + p) * OUT_CH + t * CH_PER_T;
            #pragma unroll
            for (int j = 0; j < CH_PER_T; ++j) {
                const f32x2 w0 = wp2[3*j + 0];
                const f32x2 w1 = wp2[3*j + 1];
                const f32x2 w2 = wp2[3*j + 2];

                // Windows 2i,2i+1 in one 3-inst pk chain (27 pk vs 54 scalar);
                // max over halves keeps the 9-inst v_max3 tree (halves = VGPRs).
                float m;
                #pragma unroll
                for (int i = 0; i < NPAIR; ++i) {
                    const f32x2 p2 = pk_fma(ev[i], w0,
                                     pk_fma(od[i], w1,
                                     pk_mul(ev[i + 1], w2)));
                    m = (i == 0) ? fmaxf(p2[0], p2[1])
                                 : fmaxf(fmaxf(m, p2[0]), p2[1]);   // v_max3
                }
                op[j] = m + bb[j];      // bias hoisted past max (window-invariant)
            }
        }

        // Stage slab p+1 into the other buffer; next barrier separates readers.
        if (stg && (p + 1 < NP))
            ((float4*)xs[buf ^ 1])[t] = preA;

        if (p + 1 < NP) block_sync();   // lgkmcnt-only: prefetch survives barrier
    }
}

extern "C" void kernel_launch(void* const* d_in, const int* in_sizes, int n_in,
                              void* d_out, int out_size, void* d_ws, size_t ws_size,
                              hipStream_t stream) {
    const float* x      = (const float*)d_in[0];  // [B,S,C,L] fp32
    const float* weight = (const float*)d_in[1];  // [C*F,1,W] fp32
    const float* bias   = (const float*)d_in[2];  // [C*F] fp32
    float* out          = (float*)d_out;          // [B,S,C*F] fp32

    const int nBlocks = (Bc * Sc) / NP;           // 1024 blocks
    charcnn_kernel<<<nBlocks, BLOCK, 0, stream>>>(x, weight, bias, out);
}